// Round 24
// baseline (30.789 us; speedup 1.0000x reference)
//
#include <hip/hip_runtime.h>
#include <hip/hip_bf16.h>

typedef int   v4i __attribute__((ext_vector_type(4)));
typedef float v4f __attribute__((ext_vector_type(4)));

#define HWSZ 3136   // 56*56
#define IMW  56
#define PADW 58     // 56+2 halo
#define PHW  3364   // 58*58
#define CIN  64
#define COUT 128

__device__ __forceinline__ float step_size(float a) {
    a = a > 0.f ? a : 0.f;              // relu(alpha)
    return 2.0f * a / 254.0f;
}

__device__ __forceinline__ int quant1(float x, float s) {
    float v = rintf(x / s);             // round-half-even like jnp.round
    v = fminf(127.f, fmaxf(-127.f, v)); // clip(-127, 127)
    return (int)v;
}

__device__ __forceinline__ unsigned int pack4(int a, int b, int c, int d) {
    return (unsigned int)(a & 255) | ((unsigned int)(b & 255) << 8) |
           ((unsigned int)(c & 255) << 16) | ((unsigned int)(d & 255) << 24);
}

__device__ __forceinline__ void gload_lds16(const signed char* g, signed char* l) {
    __builtin_amdgcn_global_load_lds(
        (const __attribute__((address_space(1))) void*)g,
        (__attribute__((address_space(3))) void*)l, 16, 0, 0);
}

// ---------------- fused quantize: nt-loads on the x stream ----------------
// x is read exactly once -> nontemporal loads keep the freshly written cx
// resident in L2 for conv's staging reads. Otherwise identical to R23.
__global__ __launch_bounds__(256) void quant_kernel(const float* __restrict__ x,
                                                    const float* __restrict__ w,
                                                    const float* __restrict__ alpha_x,
                                                    const float* __restrict__ alpha_w,
                                                    signed char* __restrict__ cx,
                                                    signed char* __restrict__ wt) {
    int t = threadIdx.x;
    int b = blockIdx.x;
    if (b >= 1568) {
        if (b >= 1856) {
            int q = (b - 1856) * 256 + t;
            int n = q / 912;
            int r = q % 912;
            int px = r >> 2, seg = r & 3;
            int ph, pw;
            if (px < 58)       { ph = 0;  pw = px; }
            else if (px < 116) { ph = 57; pw = px - 58; }
            else { int k = px - 116; ph = 1 + (k >> 1); pw = (k & 1) * 57; }
            v4i z = {0, 0, 0, 0};
            *(v4i*)(cx + ((size_t)n * PHW + ph * PADW + pw) * 64 + seg * 16) = z;
            return;
        }
        float s = step_size(alpha_w[0]);
        int j = (b - 1568) * 256 + t;   // wt flat index in [tap][o][c], 73728 total
        int tap = j / 8192;
        int r   = j % 8192;
        int o   = r >> 6;
        int c   = r & 63;
        float v = w[((size_t)o * 64 + c) * 9 + tap];
        wt[j] = (signed char)quant1(v, s);
        return;
    }

    // x path: one n-slice, one 64-px tile, 64 channels
    __shared__ unsigned int tile32[64 * 17];
    float s = step_size(alpha_x[0]);
    int n   = b / 49;
    int hw0 = (b % 49) * 64;
    int g   = t & 15;
    int cq  = t >> 4;
    int p   = t >> 2;
    int seg = t & 3;

    const float* xb = x + ((size_t)n * CIN + cq * 4) * HWSZ + hw0 + g * 4;
    v4f f0 = __builtin_nontemporal_load((const v4f*)(xb));
    v4f f1 = __builtin_nontemporal_load((const v4f*)(xb + HWSZ));
    v4f f2 = __builtin_nontemporal_load((const v4f*)(xb + 2 * HWSZ));
    v4f f3 = __builtin_nontemporal_load((const v4f*)(xb + 3 * HWSZ));
#pragma unroll
    for (int j = 0; j < 4; ++j) {
        unsigned int u = pack4(quant1(f0[j], s), quant1(f1[j], s),
                               quant1(f2[j], s), quant1(f3[j], s));
        tile32[(g * 4 + j) * 17 + cq] = u;
    }
    __syncthreads();
    int base = p * 17 + seg * 4;
    v4i val;
    val[0] = (int)tile32[base + 0];
    val[1] = (int)tile32[base + 1];
    val[2] = (int)tile32[base + 2];
    val[3] = (int)tile32[base + 3];
    int hw = hw0 + p;
    int h = hw / IMW, wq = hw % IMW;
    *(v4i*)(cx + ((size_t)n * PHW + (h + 1) * PADW + (wq + 1)) * 64 + seg * 16) = val;
}

// ---------------- conv (UNCHANGED from R23) ----------------
__global__ __launch_bounds__(256, 4) void conv_kernel(const signed char* __restrict__ cx,
                                                      const signed char* __restrict__ wt,
                                                      const float* __restrict__ ax,
                                                      const float* __restrict__ aw,
                                                      float* __restrict__ out) {
    __shared__ __attribute__((aligned(16))) signed char as_[34816];
    float scale = step_size(ax[0]) * step_size(aw[0]);
    int tid  = threadIdx.x;
    int lane = tid & 63;
    int wid  = tid >> 6;    // 0..3: o-quarter
    int row  = lane & 15;
    int kg   = lane >> 4;

    int bid  = blockIdx.x;
    int swz  = (bid & 7) * 196 + (bid >> 3);
    int p0   = swz * 64;
    int n    = p0 / HWSZ;
    int hw0  = p0 % HWSZ;
    int h0   = hw0 / IMW;
    int us   = h0 - 1; if (us > 52) us = 52;

    const signed char* wsrc = cx + ((size_t)n * PHW + (size_t)(us + 1) * PADW) * 64;
#pragma unroll
    for (int r = 0; r < 5; ++r) {
        int slotbase = r * 256 + wid * 64;
        gload_lds16(wsrc + (size_t)(slotbase + lane) * 16, as_ + slotbase * 16);
    }

    int obase = wid * 32;
    const signed char* wb = wt + (obase + row) * 64 + kg * 16;
    v4i breg[9][2];
#pragma unroll
    for (int tap = 0; tap < 9; ++tap)
#pragma unroll
        for (int ot = 0; ot < 2; ++ot)
            breg[tap][ot] = *(const v4i*)(wb + tap * (COUT * 64) + ot * (16 * 64));

    int lbase[4];
#pragma unroll
    for (int pt = 0; pt < 4; ++pt) {
        int hwp = hw0 + pt * 16 + row;
        int hh  = hwp / IMW, ww = hwp % IMW;
        lbase[pt] = ((hh - us) * PADW + (ww + 1)) * 64 + kg * 16;
    }

    asm volatile("s_waitcnt vmcnt(0)" ::: "memory");
    __syncthreads();
#pragma unroll
    for (int tap = 0; tap < 9; ++tap)
#pragma unroll
        for (int ot = 0; ot < 2; ++ot)
            asm volatile("" :: "v"(breg[tap][ot]));

    v4i acc[4][2] = {};
#pragma unroll
    for (int tap = 0; tap < 9; ++tap) {
        int doff = ((tap / 3 - 1) * PADW + (tap % 3 - 1)) * 64;
        v4i a[4];
#pragma unroll
        for (int pt = 0; pt < 4; ++pt)
            a[pt] = *(const v4i*)(as_ + lbase[pt] + doff);
#pragma unroll
        for (int pt = 0; pt < 4; ++pt)
#pragma unroll
            for (int ot = 0; ot < 2; ++ot)
                acc[pt][ot] = __builtin_amdgcn_mfma_i32_16x16x64_i8(a[pt], breg[tap][ot], acc[pt][ot], 0, 0, 0);
    }

    __syncthreads();
    signed char* scrw = as_ + wid * 8704;
    float* obb = out + ((size_t)n * COUT) * HWSZ + hw0;

#pragma unroll
    for (int otl = 0; otl < 2; ++otl) {
        int ol = otl * 16 + row;
#pragma unroll
        for (int pt = 0; pt < 4; ++pt) {
            int c  = pt * 4 + kg;
            int cs = c ^ (ol & 7);
            v4f v;
            v[0] = scale * (float)acc[pt][otl][0];
            v[1] = scale * (float)acc[pt][otl][1];
            v[2] = scale * (float)acc[pt][otl][2];
            v[3] = scale * (float)acc[pt][otl][3];
            *(v4f*)(scrw + ol * 272 + cs * 16) = v;
        }
    }
    {
        int og = lane >> 4;
        int c  = lane & 15;
#pragma unroll
        for (int j = 0; j < 8; ++j) {
            int ol = j * 4 + og;
            int cs = c ^ (ol & 7);
            v4f v = *(const v4f*)(scrw + ol * 272 + cs * 16);
            int o = obase + ol;
            __builtin_nontemporal_store(v, (v4f*)(obb + (size_t)o * HWSZ + c * 4));
        }
    }
}

extern "C" void kernel_launch(void* const* d_in, const int* in_sizes, int n_in,
                              void* d_out, int out_size, void* d_ws, size_t ws_size,
                              hipStream_t stream) {
    const float* x  = (const float*)d_in[0];
    const float* w  = (const float*)d_in[1];
    const float* ax = (const float*)d_in[2];
    const float* aw = (const float*)d_in[3];
    float* out = (float*)d_out;

    signed char* cx = (signed char*)d_ws;   // 32*3364*64 = 6,889,472 B (padded NHWC)
    signed char* wt = cx + 6889472;         // 9*128*64   =    73,728 B  [tap][o][c]

    quant_kernel<<<1970, 256, 0, stream>>>(x, w, ax, aw, cx, wt);
    conv_kernel<<<1568, 256, 0, stream>>>(cx, wt, ax, aw, out);
}

// Round 25
// 28.879 us; speedup vs baseline: 1.0662x; 1.0662x over previous
//
#include <hip/hip_runtime.h>
#include <hip/hip_bf16.h>

typedef int   v4i __attribute__((ext_vector_type(4)));
typedef float v4f __attribute__((ext_vector_type(4)));

#define HWSZ 3136   // 56*56
#define IMW  56
#define PADW 58     // 56+2 halo
#define PHW  3364   // 58*58
#define CIN  64
#define COUT 128

__device__ __forceinline__ float step_size(float a) {
    a = a > 0.f ? a : 0.f;              // relu(alpha)
    return 2.0f * a / 254.0f;
}

__device__ __forceinline__ int quant1(float x, float s) {
    float v = rintf(x / s);             // round-half-even like jnp.round
    v = fminf(127.f, fmaxf(-127.f, v)); // clip(-127, 127)
    return (int)v;
}

__device__ __forceinline__ unsigned int pack4(int a, int b, int c, int d) {
    return (unsigned int)(a & 255) | ((unsigned int)(b & 255) << 8) |
           ((unsigned int)(c & 255) << 16) | ((unsigned int)(d & 255) << 24);
}

__device__ __forceinline__ void gload_lds16(const signed char* g, signed char* l) {
    __builtin_amdgcn_global_load_lds(
        (const __attribute__((address_space(1))) void*)g,
        (__attribute__((address_space(3))) void*)l, 16, 0, 0);
}

// ---------------- fused quantize (R23-identical: plain loads) ----------------
__global__ __launch_bounds__(256) void quant_kernel(const float* __restrict__ x,
                                                    const float* __restrict__ w,
                                                    const float* __restrict__ alpha_x,
                                                    const float* __restrict__ alpha_w,
                                                    signed char* __restrict__ cx,
                                                    signed char* __restrict__ wt) {
    int t = threadIdx.x;
    int b = blockIdx.x;
    if (b >= 1568) {
        if (b >= 1856) {
            int q = (b - 1856) * 256 + t;
            int n = q / 912;
            int r = q % 912;
            int px = r >> 2, seg = r & 3;
            int ph, pw;
            if (px < 58)       { ph = 0;  pw = px; }
            else if (px < 116) { ph = 57; pw = px - 58; }
            else { int k = px - 116; ph = 1 + (k >> 1); pw = (k & 1) * 57; }
            v4i z = {0, 0, 0, 0};
            *(v4i*)(cx + ((size_t)n * PHW + ph * PADW + pw) * 64 + seg * 16) = z;
            return;
        }
        float s = step_size(alpha_w[0]);
        int j = (b - 1568) * 256 + t;   // wt flat index in [tap][o][c], 73728 total
        int tap = j / 8192;
        int r   = j % 8192;
        int o   = r >> 6;
        int c   = r & 63;
        float v = w[((size_t)o * 64 + c) * 9 + tap];
        wt[j] = (signed char)quant1(v, s);
        return;
    }

    // x path: one n-slice, one 64-px tile, 64 channels
    __shared__ unsigned int tile32[64 * 17];
    float s = step_size(alpha_x[0]);
    int n   = b / 49;
    int hw0 = (b % 49) * 64;
    int g   = t & 15;
    int cq  = t >> 4;
    int p   = t >> 2;
    int seg = t & 3;

    const float* xb = x + ((size_t)n * CIN + cq * 4) * HWSZ + hw0 + g * 4;
    v4f f0 = *(const v4f*)(xb);
    v4f f1 = *(const v4f*)(xb + HWSZ);
    v4f f2 = *(const v4f*)(xb + 2 * HWSZ);
    v4f f3 = *(const v4f*)(xb + 3 * HWSZ);
#pragma unroll
    for (int j = 0; j < 4; ++j) {
        unsigned int u = pack4(quant1(f0[j], s), quant1(f1[j], s),
                               quant1(f2[j], s), quant1(f3[j], s));
        tile32[(g * 4 + j) * 17 + cq] = u;
    }
    __syncthreads();
    int base = p * 17 + seg * 4;
    v4i val;
    val[0] = (int)tile32[base + 0];
    val[1] = (int)tile32[base + 1];
    val[2] = (int)tile32[base + 2];
    val[3] = (int)tile32[base + 3];
    int hw = hw0 + p;
    int h = hw / IMW, wq = hw % IMW;
    *(v4i*)(cx + ((size_t)n * PHW + (h + 1) * PADW + (wq + 1)) * 64 + seg * 16) = val;
}

// ---------------- conv (R23-identical) ----------------
__global__ __launch_bounds__(256, 4) void conv_kernel(const signed char* __restrict__ cx,
                                                      const signed char* __restrict__ wt,
                                                      const float* __restrict__ ax,
                                                      const float* __restrict__ aw,
                                                      float* __restrict__ out) {
    __shared__ __attribute__((aligned(16))) signed char as_[34816];
    float scale = step_size(ax[0]) * step_size(aw[0]);
    int tid  = threadIdx.x;
    int lane = tid & 63;
    int wid  = tid >> 6;    // 0..3: o-quarter
    int row  = lane & 15;
    int kg   = lane >> 4;

    int bid  = blockIdx.x;
    int swz  = (bid & 7) * 196 + (bid >> 3);
    int p0   = swz * 64;
    int n    = p0 / HWSZ;
    int hw0  = p0 % HWSZ;
    int h0   = hw0 / IMW;
    int us   = h0 - 1; if (us > 52) us = 52;

    const signed char* wsrc = cx + ((size_t)n * PHW + (size_t)(us + 1) * PADW) * 64;
#pragma unroll
    for (int r = 0; r < 5; ++r) {
        int slotbase = r * 256 + wid * 64;
        gload_lds16(wsrc + (size_t)(slotbase + lane) * 16, as_ + slotbase * 16);
    }

    int obase = wid * 32;
    const signed char* wb = wt + (obase + row) * 64 + kg * 16;
    v4i breg[9][2];
#pragma unroll
    for (int tap = 0; tap < 9; ++tap)
#pragma unroll
        for (int ot = 0; ot < 2; ++ot)
            breg[tap][ot] = *(const v4i*)(wb + tap * (COUT * 64) + ot * (16 * 64));

    int lbase[4];
#pragma unroll
    for (int pt = 0; pt < 4; ++pt) {
        int hwp = hw0 + pt * 16 + row;
        int hh  = hwp / IMW, ww = hwp % IMW;
        lbase[pt] = ((hh - us) * PADW + (ww + 1)) * 64 + kg * 16;
    }

    asm volatile("s_waitcnt vmcnt(0)" ::: "memory");
    __syncthreads();
#pragma unroll
    for (int tap = 0; tap < 9; ++tap)
#pragma unroll
        for (int ot = 0; ot < 2; ++ot)
            asm volatile("" :: "v"(breg[tap][ot]));

    v4i acc[4][2] = {};
#pragma unroll
    for (int tap = 0; tap < 9; ++tap) {
        int doff = ((tap / 3 - 1) * PADW + (tap % 3 - 1)) * 64;
        v4i a[4];
#pragma unroll
        for (int pt = 0; pt < 4; ++pt)
            a[pt] = *(const v4i*)(as_ + lbase[pt] + doff);
#pragma unroll
        for (int pt = 0; pt < 4; ++pt)
#pragma unroll
            for (int ot = 0; ot < 2; ++ot)
                acc[pt][ot] = __builtin_amdgcn_mfma_i32_16x16x64_i8(a[pt], breg[tap][ot], acc[pt][ot], 0, 0, 0);
    }

    __syncthreads();
    signed char* scrw = as_ + wid * 8704;
    float* obb = out + ((size_t)n * COUT) * HWSZ + hw0;

#pragma unroll
    for (int otl = 0; otl < 2; ++otl) {
        int ol = otl * 16 + row;
#pragma unroll
        for (int pt = 0; pt < 4; ++pt) {
            int c  = pt * 4 + kg;
            int cs = c ^ (ol & 7);
            v4f v;
            v[0] = scale * (float)acc[pt][otl][0];
            v[1] = scale * (float)acc[pt][otl][1];
            v[2] = scale * (float)acc[pt][otl][2];
            v[3] = scale * (float)acc[pt][otl][3];
            *(v4f*)(scrw + ol * 272 + cs * 16) = v;
        }
    }
    {
        int og = lane >> 4;
        int c  = lane & 15;
#pragma unroll
        for (int j = 0; j < 8; ++j) {
            int ol = j * 4 + og;
            int cs = c ^ (ol & 7);
            v4f v = *(const v4f*)(scrw + ol * 272 + cs * 16);
            int o = obase + ol;
            __builtin_nontemporal_store(v, (v4f*)(obb + (size_t)o * HWSZ + c * 4));
        }
    }
}

extern "C" void kernel_launch(void* const* d_in, const int* in_sizes, int n_in,
                              void* d_out, int out_size, void* d_ws, size_t ws_size,
                              hipStream_t stream) {
    const float* x  = (const float*)d_in[0];
    const float* w  = (const float*)d_in[1];
    const float* ax = (const float*)d_in[2];
    const float* aw = (const float*)d_in[3];
    float* out = (float*)d_out;

    signed char* cx = (signed char*)d_ws;   // 32*3364*64 = 6,889,472 B (padded NHWC)
    signed char* wt = cx + 6889472;         // 9*128*64   =    73,728 B  [tap][o][c]

    quant_kernel<<<1970, 256, 0, stream>>>(x, w, ax, aw, cx, wt);
    conv_kernel<<<1568, 256, 0, stream>>>(cx, wt, ax, aw, out);
}